// Round 1
// baseline (492.861 us; speedup 1.0000x reference)
//
#include <hip/hip_runtime.h>
#include <hip/hip_bf16.h>

#define LRALPHA 0.2f

constexpr int Bb = 8;
constexpr int NN = 2048;
constexpr int FIN = 512;
constexpr int FOUT = 256;

// ---------------------------------------------------------------------------
// Kernel A: h = x @ W   (M=16384, K=512, N=256, fp32)
// 64x64 tile, BK=16, 256 threads, 4x4 micro-tile per thread.
// ---------------------------------------------------------------------------
__global__ __launch_bounds__(256) void gemm_xw(const float* __restrict__ x,
                                               const float* __restrict__ W,
                                               float* __restrict__ h) {
    __shared__ float As[16][68];   // [k][m], padded to 68 to spread banks
    __shared__ float Bs[16][68];   // [k][n], padded

    const int t  = threadIdx.x;
    const int m0 = blockIdx.y * 64;
    const int n0 = blockIdx.x * 64;
    const int tm = t & 15, tn = t >> 4;      // micro-tile coords
    const int arow = t >> 2, akq = (t & 3) * 4;  // A-load coords
    const int bk = t >> 4, bn4 = (t & 15) * 4;   // B-load coords

    float acc[4][4] = {};

    for (int k0 = 0; k0 < FIN; k0 += 16) {
        const float4 av = *(const float4*)&x[(size_t)(m0 + arow) * FIN + k0 + akq];
        const float4 bv = *(const float4*)&W[(size_t)(k0 + bk) * FOUT + n0 + bn4];
        __syncthreads();   // previous iteration done reading LDS
        As[akq + 0][arow] = av.x;
        As[akq + 1][arow] = av.y;
        As[akq + 2][arow] = av.z;
        As[akq + 3][arow] = av.w;
        *(float4*)&Bs[bk][bn4] = bv;
        __syncthreads();
#pragma unroll
        for (int kk = 0; kk < 16; ++kk) {
            const float4 a = *(const float4*)&As[kk][tm * 4];
            const float4 b = *(const float4*)&Bs[kk][tn * 4];
            const float* ap = &a.x;
            const float* bp = &b.x;
#pragma unroll
            for (int i = 0; i < 4; ++i)
#pragma unroll
                for (int j = 0; j < 4; ++j)
                    acc[i][j] = fmaf(ap[i], bp[j], acc[i][j]);
        }
    }
#pragma unroll
    for (int i = 0; i < 4; ++i) {
        *(float4*)&h[(size_t)(m0 + tm * 4 + i) * FOUT + n0 + tn * 4] =
            make_float4(acc[i][0], acc[i][1], acc[i][2], acc[i][3]);
    }
}

// ---------------------------------------------------------------------------
// Kernel B: s[row] = h[row,:] . a1 ; t[row] = h[row,:] . a2
// one wave per row (64 lanes x float4 = 256 channels)
// ---------------------------------------------------------------------------
__global__ __launch_bounds__(256) void rowdots(const float* __restrict__ h,
                                               const float* __restrict__ a,
                                               float* __restrict__ sv,
                                               float* __restrict__ tv) {
    const int row  = blockIdx.x * 4 + (threadIdx.x >> 6);
    const int lane = threadIdx.x & 63;
    const float4 hv = *(const float4*)&h[(size_t)row * FOUT + lane * 4];
    const float4 a1 = *(const float4*)&a[lane * 4];
    const float4 a2 = *(const float4*)&a[FOUT + lane * 4];
    float sp = hv.x * a1.x + hv.y * a1.y + hv.z * a1.z + hv.w * a1.w;
    float tp = hv.x * a2.x + hv.y * a2.y + hv.z * a2.z + hv.w * a2.w;
#pragma unroll
    for (int off = 32; off > 0; off >>= 1) {
        sp += __shfl_down(sp, off);
        tp += __shfl_down(tp, off);
    }
    if (lane == 0) { sv[row] = sp; tv[row] = tp; }
}

// ---------------------------------------------------------------------------
// Kernel C: fused masked-softmax attention + weighted sum + elu.
// Block: 512 threads, 64 query rows (one b, one 64-row tile). Sweep j in
// 32-wide tiles: stage h[j-tile] in LDS (global_load_lds w=16), compute
// w = adj ? exp(lrelu(s_i+t_j)) : 0 into LDS, accumulate num += w*h in regs.
// No max-subtraction needed: |s+t| <~ 20, exp fits fp32 easily; masked
// weights are exactly 0 (== reference's exp(NEG_INF - m)).
// ---------------------------------------------------------------------------
__global__ __launch_bounds__(512) void gat_fused(const float* __restrict__ h,
                                                 const int* __restrict__ adj,
                                                 const float* __restrict__ sv,
                                                 const float* __restrict__ tv,
                                                 float* __restrict__ out) {
    constexpr int TJ = 32, BI = 64, NT = NN / TJ;
    __shared__ float hs[TJ][FOUT];     // 32 KB  h tile [j][c]
    __shared__ float wst[TJ][BI];      //  8 KB  weights [j][i]
    __shared__ float tl[NN];           //  8 KB  t vector for this b
    __shared__ float den_lds[BI];

    const int t  = threadIdx.x;
    const int b  = blockIdx.y;
    const int i0 = blockIdx.x * BI;

    // stage t[b,:] once
    *(float4*)&tl[t * 4] = *(const float4*)&tv[b * NN + t * 4];

    // weight-compute mapping: thread -> (row iw, 4 j's)
    const int iw = t >> 3, js = t & 7;
    const float sw = sv[b * NN + i0 + iw];
    const int* adj_row = adj + ((size_t)b * NN + i0 + iw) * NN;

    // accumulation mapping: thread -> (4 rows, 8 channels split c0/c1)
    const int ig = t >> 5, cg = t & 31;
    const int c0 = cg * 4, c1 = 128 + cg * 4;   // split avoids stride-32B LDS pattern
    const int wv = t >> 6, ln = t & 63;
    const float* hb = h + (size_t)b * NN * FOUT;

    float num[4][8] = {};
    float den_part = 0.f;

    __syncthreads();   // tl ready

    int4 adjv = *(const int4*)&adj_row[js * 4];   // tile 0 prefetch

    for (int tt = 0; tt < NT; ++tt) {
        const int j0 = tt * TJ;
        // async stage h tile: 32 chunks x (64 lanes x 16B) = 32 KB
#pragma unroll
        for (int q = 0; q < 4; ++q) {
            const int chunk = q * 8 + wv;
            __builtin_amdgcn_global_load_lds(
                (const __attribute__((address_space(1))) unsigned int*)
                    (hb + (size_t)j0 * FOUT + chunk * 256 + ln * 4),
                (__attribute__((address_space(3))) unsigned int*)
                    (&hs[0][0] + chunk * 256),
                16, 0, 0);
        }
        // prefetch next adj tile (register)
        int4 adj_nxt = make_int4(0, 0, 0, 0);
        if (tt + 1 < NT) adj_nxt = *(const int4*)&adj_row[j0 + TJ + js * 4];

        // weights for this tile
        const int* avp = &adjv.x;
#pragma unroll
        for (int q = 0; q < 4; ++q) {
            const int jj = js * 4 + q;
            float v = sw + tl[j0 + jj];
            v = v > 0.f ? v : LRALPHA * v;
            const float w = (avp[q] > 0) ? __expf(v) : 0.f;
            den_part += w;
            wst[jj][iw] = w;
        }
        __syncthreads();   // hs (vmcnt drain) + wst ready

        // accumulate: 4 rows x 8 channels per thread
#pragma unroll 4
        for (int jj = 0; jj < TJ; ++jj) {
            const float4 wa = *(const float4*)&wst[jj][ig * 4];
            const float4 ha = *(const float4*)&hs[jj][c0];
            const float4 hc = *(const float4*)&hs[jj][c1];
            const float* wap = &wa.x;
            const float* hap = &ha.x;
            const float* hcp = &hc.x;
#pragma unroll
            for (int r = 0; r < 4; ++r) {
#pragma unroll
                for (int q = 0; q < 4; ++q) {
                    num[r][q]     = fmaf(wap[r], hap[q], num[r][q]);
                    num[r][4 + q] = fmaf(wap[r], hcp[q], num[r][4 + q]);
                }
            }
        }
        __syncthreads();   // done with hs/wst before next tile overwrites
        adjv = adj_nxt;
    }

    // denominator: reduce the 8 partials per row (lanes share iw in groups of 8)
    den_part += __shfl_down(den_part, 1, 8);
    den_part += __shfl_down(den_part, 2, 8);
    den_part += __shfl_down(den_part, 4, 8);
    if (js == 0) den_lds[iw] = den_part;
    __syncthreads();

    // epilogue: normalize + elu + store
#pragma unroll
    for (int r = 0; r < 4; ++r) {
        const int il = ig * 4 + r;
        const float inv = 1.0f / den_lds[il];
        float o[8];
#pragma unroll
        for (int q = 0; q < 8; ++q) {
            const float v = num[r][q] * inv;
            o[q] = v > 0.f ? v : expm1f(v);
        }
        float* op = out + ((size_t)b * NN + i0 + il) * FOUT;
        *(float4*)&op[c0] = make_float4(o[0], o[1], o[2], o[3]);
        *(float4*)&op[c1] = make_float4(o[4], o[5], o[6], o[7]);
    }
}

// ---------------------------------------------------------------------------
extern "C" void kernel_launch(void* const* d_in, const int* in_sizes, int n_in,
                              void* d_out, int out_size, void* d_ws, size_t ws_size,
                              hipStream_t stream) {
    const float* x   = (const float*)d_in[0];
    const int*   adj = (const int*)d_in[1];
    const float* W   = (const float*)d_in[2];
    const float* a   = (const float*)d_in[3];
    float* out = (float*)d_out;

    // workspace layout: h (16 MB) | s (64 KB) | t (64 KB)  => ~16.9 MB
    float* h  = (float*)d_ws;
    float* sv = h + (size_t)Bb * NN * FOUT;
    float* tv = sv + (size_t)Bb * NN;

    gemm_xw<<<dim3(FOUT / 64, (Bb * NN) / 64), 256, 0, stream>>>(x, W, h);
    rowdots<<<(Bb * NN) / 4, 256, 0, stream>>>(h, a, sv, tv);
    gat_fused<<<dim3(NN / 64, Bb), 512, 0, stream>>>(h, adj, sv, tv, out);
}

// Round 2
// 343.984 us; speedup vs baseline: 1.4328x; 1.4328x over previous
//
#include <hip/hip_runtime.h>
#include <hip/hip_bf16.h>

typedef __attribute__((ext_vector_type(8))) short short8;
typedef __attribute__((ext_vector_type(4))) float f32x4;

constexpr int Bb = 8, NN = 2048, FIN = 512, FOUT = 256;
#define LRALPHA 0.2f

__device__ __forceinline__ ushort f2bf(float f) {
    unsigned u = __float_as_uint(f);
    u += 0x7fffu + ((u >> 16) & 1u);
    return (ushort)(u >> 16);
}
__device__ __forceinline__ float bf2f(ushort b) {
    return __uint_as_float(((unsigned)b) << 16);
}

#define GLOAD16(gp, lp) __builtin_amdgcn_global_load_lds( \
    (const __attribute__((address_space(1))) unsigned int*)(gp), \
    (__attribute__((address_space(3))) unsigned int*)(lp), 16, 0, 0)

#define MFMA16(a, b, c) __builtin_amdgcn_mfma_f32_16x16x32_bf16((a), (b), (c), 0, 0, 0)

// ---------------------------------------------------------------------------
// K0: W [512][256] fp32 -> WT_hi/WT_lo [256][512] bf16 (split precision).
// grid 256 (one block per output row n) so each WT cache line has one writer.
// ---------------------------------------------------------------------------
__global__ __launch_bounds__(256) void prep_w(const float* __restrict__ W,
                                              ushort* __restrict__ WTh,
                                              ushort* __restrict__ WTl) {
    const int n = blockIdx.x;
    const int t = threadIdx.x;
    for (int k = t; k < FIN; k += 256) {
        const float w = W[(size_t)k * FOUT + n];
        const ushort hi = f2bf(w);
        WTh[(size_t)n * FIN + k] = hi;
        WTl[(size_t)n * FIN + k] = f2bf(w - bf2f(hi));
    }
}

// ---------------------------------------------------------------------------
// K1: h = x @ W via split-bf16 MFMA (3 terms: xh*wh + xh*wl + xl*wh).
// Tile 128m x 128n, BK=64, 512 threads (8 waves, wave w owns n-frag w).
// A staged fp32->hi/lo in fragment order (conflict-free b128 LDS);
// B staged from WT hi/lo via global_load_lds in fragment order.
// gid: m = gid&127, n = gid>>7 -> both n-tiles of same m on same XCD (x L2 reuse).
// ---------------------------------------------------------------------------
__global__ __launch_bounds__(512) void gemm_xw(const float* __restrict__ x,
                                               const ushort* __restrict__ WTh,
                                               const ushort* __restrict__ WTl,
                                               float* __restrict__ h) {
    __shared__ ushort Ah[8][2][512];   // [ifrag][kstep][lane*8] 16KB
    __shared__ ushort Al[8][2][512];
    __shared__ ushort Bh[8][2][512];   // [cfrag][kstep][lane*8]
    __shared__ ushort Bl[8][2][512];

    const int t = threadIdx.x;
    const int lane = t & 63, w = t >> 6;
    const int m0 = (blockIdx.x & 127) * 128;
    const int n0 = (blockIdx.x >> 7) * 128;

    f32x4 acc[8];
#pragma unroll
    for (int f = 0; f < 8; ++f) acc[f] = (f32x4){0.f, 0.f, 0.f, 0.f};

    // B gload per-lane base (elements into WT[256][512])
    const size_t bcol = (size_t)(n0 + w * 16 + (lane & 15)) * FIN + (lane >> 4) * 8;

    for (int kt = 0; kt < 8; ++kt) {
        const int k0 = kt * 64;
        // --- issue B stage (async) ---
#pragma unroll
        for (int ks = 0; ks < 2; ++ks) {
            GLOAD16(WTh + bcol + k0 + ks * 32, &Bh[w][ks][0]);
            GLOAD16(WTl + bcol + k0 + ks * 32, &Bl[w][ks][0]);
        }
        // --- A stage: 2 fragment-chunks per thread, convert fp32 -> hi/lo ---
#pragma unroll
        for (int h2 = 0; h2 < 2; ++h2) {
            const int q = t + h2 * 512;
            const int ql = q & 63, qks = (q >> 6) & 1, qif = q >> 7;
            const float* xp = x + (size_t)(m0 + qif * 16 + (ql & 15)) * FIN
                              + k0 + qks * 32 + (ql >> 4) * 8;
            const float4 f0 = *(const float4*)xp;
            const float4 f1 = *(const float4*)(xp + 4);
            float fv[8] = {f0.x, f0.y, f0.z, f0.w, f1.x, f1.y, f1.z, f1.w};
            short8 vh, vl;
#pragma unroll
            for (int e = 0; e < 8; ++e) {
                const ushort hb = f2bf(fv[e]);
                vh[e] = (short)hb;
                vl[e] = (short)f2bf(fv[e] - bf2f(hb));
            }
            *(short8*)&Ah[qif][qks][ql * 8] = vh;
            *(short8*)&Al[qif][qks][ql * 8] = vl;
        }
        __syncthreads();   // staging (gload vmcnt + ds writes) complete
        const short8 bh0 = *(const short8*)&Bh[w][0][lane * 8];
        const short8 bl0 = *(const short8*)&Bl[w][0][lane * 8];
        const short8 bh1 = *(const short8*)&Bh[w][1][lane * 8];
        const short8 bl1 = *(const short8*)&Bl[w][1][lane * 8];
#pragma unroll
        for (int f = 0; f < 8; ++f) {
            const short8 ah0 = *(const short8*)&Ah[f][0][lane * 8];
            const short8 al0 = *(const short8*)&Al[f][0][lane * 8];
            const short8 ah1 = *(const short8*)&Ah[f][1][lane * 8];
            const short8 al1 = *(const short8*)&Al[f][1][lane * 8];
            acc[f] = MFMA16(ah0, bh0, acc[f]);
            acc[f] = MFMA16(ah0, bl0, acc[f]);
            acc[f] = MFMA16(al0, bh0, acc[f]);
            acc[f] = MFMA16(ah1, bh1, acc[f]);
            acc[f] = MFMA16(ah1, bl1, acc[f]);
            acc[f] = MFMA16(al1, bh1, acc[f]);
        }
        __syncthreads();   // done reading LDS before next tile overwrites
    }
    // epilogue: D layout col=lane&15, row=(lane>>4)*4+r
    const int rb = (lane >> 4) * 4;
    const int cc = n0 + w * 16 + (lane & 15);
#pragma unroll
    for (int f = 0; f < 8; ++f)
#pragma unroll
        for (int r = 0; r < 4; ++r)
            h[(size_t)(m0 + f * 16 + rb + r) * FOUT + cc] = acc[f][r];
}

// ---------------------------------------------------------------------------
// K2: h fp32 -> hT_hi/hT_lo [b][c][j] bf16 (transposed, split) + s,t row dots.
// Block: one (b, 32-row j-tile); 256 threads.
// ---------------------------------------------------------------------------
__global__ __launch_bounds__(256) void trans_dots(const float* __restrict__ h,
                                                  const float* __restrict__ a,
                                                  ushort* __restrict__ hTh,
                                                  ushort* __restrict__ hTl,
                                                  float* __restrict__ sv,
                                                  float* __restrict__ tv) {
    __shared__ ushort Th[32][264];
    __shared__ ushort Tl[32][264];
    const int t = threadIdx.x;
    const int jt = blockIdx.x & 63, b = blockIdx.x >> 6;
    const int j0 = jt * 32;
    const int row = t >> 3, cb = (t & 7) * 32;

    const float* hp = h + (size_t)(b * NN + j0 + row) * FOUT + cb;
    float sp = 0.f, tp = 0.f;
#pragma unroll
    for (int q = 0; q < 8; ++q) {
        const float4 xv = *(const float4*)(hp + q * 4);
        const float4 a1 = *(const float4*)(a + cb + q * 4);
        const float4 a2 = *(const float4*)(a + FOUT + cb + q * 4);
        sp += xv.x * a1.x + xv.y * a1.y + xv.z * a1.z + xv.w * a1.w;
        tp += xv.x * a2.x + xv.y * a2.y + xv.z * a2.z + xv.w * a2.w;
        float fv[4] = {xv.x, xv.y, xv.z, xv.w};
        ushort4 hv, lv;
        ushort* hvp = &hv.x; ushort* lvp = &lv.x;
#pragma unroll
        for (int e = 0; e < 4; ++e) {
            const ushort hb = f2bf(fv[e]);
            hvp[e] = hb;
            lvp[e] = f2bf(fv[e] - bf2f(hb));
        }
        *(ushort4*)&Th[row][cb + q * 4] = hv;
        *(ushort4*)&Tl[row][cb + q * 4] = lv;
    }
    sp += __shfl_down(sp, 1, 8); sp += __shfl_down(sp, 2, 8); sp += __shfl_down(sp, 4, 8);
    tp += __shfl_down(tp, 1, 8); tp += __shfl_down(tp, 2, 8); tp += __shfl_down(tp, 4, 8);
    if ((t & 7) == 0) {
        sv[b * NN + j0 + row] = sp;
        tv[b * NN + j0 + row] = tp;
    }
    __syncthreads();
    // transpose out: thread t = channel c, write 32 j's (64B) contiguous
    ushort* dh = hTh + (size_t)(b * FOUT + t) * NN + j0;
    ushort* dl = hTl + (size_t)(b * FOUT + t) * NN + j0;
#pragma unroll
    for (int g = 0; g < 4; ++g) {
        uint4 vh4, vl4;
        vh4.x = (uint)Th[g * 8 + 0][t] | ((uint)Th[g * 8 + 1][t] << 16);
        vh4.y = (uint)Th[g * 8 + 2][t] | ((uint)Th[g * 8 + 3][t] << 16);
        vh4.z = (uint)Th[g * 8 + 4][t] | ((uint)Th[g * 8 + 5][t] << 16);
        vh4.w = (uint)Th[g * 8 + 6][t] | ((uint)Th[g * 8 + 7][t] << 16);
        vl4.x = (uint)Tl[g * 8 + 0][t] | ((uint)Tl[g * 8 + 1][t] << 16);
        vl4.y = (uint)Tl[g * 8 + 2][t] | ((uint)Tl[g * 8 + 3][t] << 16);
        vl4.z = (uint)Tl[g * 8 + 4][t] | ((uint)Tl[g * 8 + 5][t] << 16);
        vl4.w = (uint)Tl[g * 8 + 6][t] | ((uint)Tl[g * 8 + 7][t] << 16);
        *(uint4*)(dh + g * 8) = vh4;
        *(uint4*)(dl + g * 8) = vl4;
    }
}

// ---------------------------------------------------------------------------
// K3: fused masked softmax + (P @ H) via MFMA + elu.
// Block = (b = gid&7 for XCD L2 affinity, 64 i-rows). 512 threads, 8 waves.
// Per 64-j tile: stage H hi/lo fragments via global_load_lds (frag order),
// compute w = adj ? exp(lrelu(s_i+t_j)) : 0, round to bf16 (den sums the
// ROUNDED values so weights sum to exactly 1), write P fragments to LDS,
// then 32 MFMAs/wave. Normalize + elu in epilogue.
// ---------------------------------------------------------------------------
__global__ __launch_bounds__(512) void gat_fused(const int* __restrict__ adj,
                                                 const ushort* __restrict__ hTh,
                                                 const ushort* __restrict__ hTl,
                                                 const float* __restrict__ sv,
                                                 const float* __restrict__ tv,
                                                 float* __restrict__ out) {
    __shared__ float t_l[NN];           // 8KB
    __shared__ ushort Pf[4][2][512];    // 8KB  A-frags (bf16 weights)
    __shared__ ushort Hh[16][2][512];   // 32KB B-frags hi
    __shared__ ushort Hl[16][2][512];   // 32KB B-frags lo
    __shared__ float den_l[64];

    const int t = threadIdx.x, lane = t & 63, w = t >> 6;
    const int b = blockIdx.x & 7, i0 = (blockIdx.x >> 3) * 64;

    // stage t vector for this b
    *(float4*)&t_l[t * 4] = *(const float4*)&tv[b * NN + t * 4];

    // P-writer mapping: thread -> (row pi, 8 j's at pjs*8)
    const int pi = t >> 3, pjs = t & 7;
    const float s_i = sv[b * NN + i0 + pi];
    const int* adjp = adj + (size_t)(b * NN + i0 + pi) * NN + pjs * 8;
    ushort* pdst = &Pf[pi >> 4][pjs >> 2][(((pjs & 3) << 4) | (pi & 15)) * 8];

    // H gload per-lane bases (elements into hT[b][256][2048])
    const int cfa = 2 * w, cfb = 2 * w + 1;
    const size_t ga = (size_t)(b * FOUT + cfa * 16 + (lane & 15)) * NN + (lane >> 4) * 8;
    const size_t gb = (size_t)(b * FOUT + cfb * 16 + (lane & 15)) * NN + (lane >> 4) * 8;

    f32x4 acc[4][2];
#pragma unroll
    for (int f = 0; f < 4; ++f) {
        acc[f][0] = (f32x4){0.f, 0.f, 0.f, 0.f};
        acc[f][1] = (f32x4){0.f, 0.f, 0.f, 0.f};
    }
    float den_part = 0.f;

    __syncthreads();   // t_l ready

    int4 aj0 = *(const int4*)&adjp[0];
    int4 aj1 = *(const int4*)&adjp[4];

    for (int tt = 0; tt < NN / 64; ++tt) {
        const int j0 = tt * 64;
        // --- issue H fragment staging (async, 8 gloads per wave) ---
#pragma unroll
        for (int ks = 0; ks < 2; ++ks) {
            GLOAD16(hTh + ga + j0 + ks * 32, &Hh[cfa][ks][0]);
            GLOAD16(hTl + ga + j0 + ks * 32, &Hl[cfa][ks][0]);
            GLOAD16(hTh + gb + j0 + ks * 32, &Hh[cfb][ks][0]);
            GLOAD16(hTl + gb + j0 + ks * 32, &Hl[cfb][ks][0]);
        }
        // --- prefetch next tile's adj ---
        int4 an0 = make_int4(0, 0, 0, 0), an1 = make_int4(0, 0, 0, 0);
        if (tt + 1 < NN / 64) {
            an0 = *(const int4*)&adjp[j0 + 64];
            an1 = *(const int4*)&adjp[j0 + 68];
        }
        // --- compute 8 weights, round to bf16, write P fragment ---
        const int mv[8] = {aj0.x, aj0.y, aj0.z, aj0.w, aj1.x, aj1.y, aj1.z, aj1.w};
        short8 pv;
#pragma unroll
        for (int e = 0; e < 8; ++e) {
            float v = s_i + t_l[j0 + pjs * 8 + e];
            v = v > 0.f ? v : LRALPHA * v;
            const float ww = (mv[e] > 0) ? __expf(v) : 0.f;
            const ushort hb = f2bf(ww);
            den_part += bf2f(hb);
            pv[e] = (short)hb;
        }
        *(short8*)pdst = pv;
        __syncthreads();   // gloads drained + P written

        // --- MFMA: 4 ifrag x 2 cfrag x 2 kstep x (hi+lo) ---
        const short8 b0h0 = *(const short8*)&Hh[cfa][0][lane * 8];
        const short8 b0l0 = *(const short8*)&Hl[cfa][0][lane * 8];
        const short8 b0h1 = *(const short8*)&Hh[cfa][1][lane * 8];
        const short8 b0l1 = *(const short8*)&Hl[cfa][1][lane * 8];
        const short8 b1h0 = *(const short8*)&Hh[cfb][0][lane * 8];
        const short8 b1l0 = *(const short8*)&Hl[cfb][0][lane * 8];
        const short8 b1h1 = *(const short8*)&Hh[cfb][1][lane * 8];
        const short8 b1l1 = *(const short8*)&Hl[cfb][1][lane * 8];
#pragma unroll
        for (int f = 0; f < 4; ++f) {
            const short8 a0 = *(const short8*)&Pf[f][0][lane * 8];
            const short8 a1 = *(const short8*)&Pf[f][1][lane * 8];
            acc[f][0] = MFMA16(a0, b0h0, acc[f][0]);
            acc[f][0] = MFMA16(a0, b0l0, acc[f][0]);
            acc[f][0] = MFMA16(a1, b0h1, acc[f][0]);
            acc[f][0] = MFMA16(a1, b0l1, acc[f][0]);
            acc[f][1] = MFMA16(a0, b1h0, acc[f][1]);
            acc[f][1] = MFMA16(a0, b1l0, acc[f][1]);
            acc[f][1] = MFMA16(a1, b1h1, acc[f][1]);
            acc[f][1] = MFMA16(a1, b1l1, acc[f][1]);
        }
        __syncthreads();   // done with LDS before next tile overwrites
        aj0 = an0; aj1 = an1;
    }

    // --- denominator: reduce 8 j-slices per row (consecutive lanes) ---
    float d = den_part;
    d += __shfl_down(d, 1, 8); d += __shfl_down(d, 2, 8); d += __shfl_down(d, 4, 8);
    if (pjs == 0) den_l[pi] = d;
    __syncthreads();

    // --- epilogue: normalize + elu + store ---
    const int rb = (lane >> 4) * 4;
    const int cbase = w * 32 + (lane & 15);
#pragma unroll
    for (int f = 0; f < 4; ++f) {
#pragma unroll
        for (int cfi = 0; cfi < 2; ++cfi) {
#pragma unroll
            for (int r = 0; r < 4; ++r) {
                const int row = f * 16 + rb + r;
                float v = acc[f][cfi][r] / den_l[row];
                v = v > 0.f ? v : expm1f(v);
                out[(size_t)(b * NN + i0 + row) * FOUT + cbase + cfi * 16] = v;
            }
        }
    }
}

// ---------------------------------------------------------------------------
extern "C" void kernel_launch(void* const* d_in, const int* in_sizes, int n_in,
                              void* d_out, int out_size, void* d_ws, size_t ws_size,
                              hipStream_t stream) {
    const float* x   = (const float*)d_in[0];
    const int*   adj = (const int*)d_in[1];
    const float* W   = (const float*)d_in[2];
    const float* a   = (const float*)d_in[3];
    float* out = (float*)d_out;

    // workspace: h fp32 16MB | hT_hi 8MB | hT_lo 8MB | s 64KB | t 64KB | WT 0.5MB
    float*  h   = (float*)d_ws;
    ushort* hTh = (ushort*)(h + (size_t)Bb * NN * FOUT);
    ushort* hTl = hTh + (size_t)Bb * FOUT * NN;
    float*  sv  = (float*)(hTl + (size_t)Bb * FOUT * NN);
    float*  tv  = sv + Bb * NN;
    ushort* WTh = (ushort*)(tv + Bb * NN);
    ushort* WTl = WTh + (size_t)FIN * FOUT;

    prep_w<<<256, 256, 0, stream>>>(W, WTh, WTl);
    gemm_xw<<<256, 512, 0, stream>>>(x, WTh, WTl, h);
    trans_dots<<<512, 256, 0, stream>>>(h, a, hTh, hTl, sv, tv);
    gat_fused<<<256, 512, 0, stream>>>(adj, hTh, hTl, sv, tv, out);
}

// Round 3
// 298.466 us; speedup vs baseline: 1.6513x; 1.1525x over previous
//
#include <hip/hip_runtime.h>
#include <hip/hip_bf16.h>

typedef __attribute__((ext_vector_type(8))) short short8;
typedef __attribute__((ext_vector_type(4))) short short4v;
typedef __attribute__((ext_vector_type(4))) float f32x4;

constexpr int Bb = 8, NN = 2048, FIN = 512, FOUT = 256;
#define LRALPHA 0.2f
#define MFMA16(a, b, c) __builtin_amdgcn_mfma_f32_16x16x32_bf16((a), (b), (c), 0, 0, 0)

__device__ __forceinline__ ushort f2bf(float f) {
    unsigned u = __float_as_uint(f);
    u += 0x7fffu + ((u >> 16) & 1u);
    return (ushort)(u >> 16);
}
__device__ __forceinline__ float bf2f(ushort b) { return __uint_as_float(((unsigned)b) << 16); }

// ---------------------------------------------------------------------------
// K0: W[512][256] fp32 -> WTh/WTl [256][512] bf16 hi/lo split.
// ---------------------------------------------------------------------------
__global__ __launch_bounds__(256) void prep_w(const float* __restrict__ W,
                                              ushort* __restrict__ WTh,
                                              ushort* __restrict__ WTl) {
    const int n = blockIdx.x, t = threadIdx.x;
    for (int k = t; k < FIN; k += 256) {
        const float w = W[(size_t)k * FOUT + n];
        const ushort hi = f2bf(w);
        WTh[(size_t)n * FIN + k] = hi;
        WTl[(size_t)n * FIN + k] = f2bf(w - bf2f(hi));
    }
}

// ---------------------------------------------------------------------------
// K1: h = x @ W (2-term split: xh*(Wh+Wl)), FUSED epilogue:
//   - writes hT bf16 [b][c][j] (transposed via per-wave LDS transpose)
//   - s/t row dots via shfl-reduce + atomicAdd (sv/tv pre-zeroed)
// Tile 64m x 128n, BK=64, 512 thr / 8 waves (wave w -> cfrag w).
// B operand: direct global->reg (WT is L2-resident, frag-order addresses).
// A operand: fp32->bf16 convert + frag-order LDS (conflict-free b128).
// grid 512 -> 2 blocks/CU.
// ---------------------------------------------------------------------------
__global__ __launch_bounds__(512, 4) void gemm_h(const float* __restrict__ x,
                                                 const ushort* __restrict__ WTh,
                                                 const ushort* __restrict__ WTl,
                                                 const float* __restrict__ a,
                                                 ushort* __restrict__ hTh,
                                                 float* __restrict__ sv,
                                                 float* __restrict__ tv) {
    __shared__ ushort Ah[4][2][512];   // 8 KB  A frags (bf16 hi)
    __shared__ ushort Tr[8][16][72];   // 18.4 KB transpose buffer (72: 16B-aligned + odd-ish banks)

    const int t = threadIdx.x, lane = t & 63, w = t >> 6;
    const int m0 = (blockIdx.x >> 1) * 64;
    const int n0 = (blockIdx.x & 1) * 128;

    // A-stage mapping: thread -> (ifrag qif, kstep qks, frag-lane ql)
    const int ql = t & 63, qks = (t >> 6) & 1, qif = t >> 7;
    const float* xp = x + (size_t)(m0 + qif * 16 + (ql & 15)) * FIN + qks * 32 + (ql >> 4) * 8;

    // B direct-reg frag addresses
    const size_t boff = (size_t)(n0 + w * 16 + (lane & 15)) * FIN + (lane >> 4) * 8;
    const ushort* bph = WTh + boff;
    const ushort* bpl = WTl + boff;

    f32x4 acc[4];
#pragma unroll
    for (int f = 0; f < 4; ++f) acc[f] = (f32x4){0.f, 0.f, 0.f, 0.f};

    for (int kt = 0; kt < 8; ++kt) {
        const int k0 = kt * 64;
        // B regs (independent of barriers)
        const short8 bh0 = *(const short8*)(bph + k0);
        const short8 bl0 = *(const short8*)(bpl + k0);
        const short8 bh1 = *(const short8*)(bph + k0 + 32);
        const short8 bl1 = *(const short8*)(bpl + k0 + 32);
        // A load + convert
        const float4 f0 = *(const float4*)(xp + k0);
        const float4 f1 = *(const float4*)(xp + k0 + 4);
        const float fv[8] = {f0.x, f0.y, f0.z, f0.w, f1.x, f1.y, f1.z, f1.w};
        short8 vh;
#pragma unroll
        for (int e = 0; e < 8; ++e) vh[e] = (short)f2bf(fv[e]);
        __syncthreads();                       // WAR: prev iter's reads done
        *(short8*)&Ah[qif][qks][ql * 8] = vh;
        __syncthreads();                       // RAW: A staged
#pragma unroll
        for (int f = 0; f < 4; ++f) {
            const short8 a0 = *(const short8*)&Ah[f][0][lane * 8];
            const short8 a1 = *(const short8*)&Ah[f][1][lane * 8];
            acc[f] = MFMA16(a0, bh0, acc[f]);
            acc[f] = MFMA16(a0, bl0, acc[f]);
            acc[f] = MFMA16(a1, bh1, acc[f]);
            acc[f] = MFMA16(a1, bl1, acc[f]);
        }
    }

    // ---- epilogue: s/t dots (shfl reduce over 16 cols, atomicAdd) ----
    const int cc = n0 + w * 16 + (lane & 15);
    const float a1v = a[cc], a2v = a[FOUT + cc];
    const int rb = (lane >> 4) * 4;
#pragma unroll
    for (int f = 0; f < 4; ++f) {
#pragma unroll
        for (int r = 0; r < 4; ++r) {
            float v1 = acc[f][r] * a1v;
            float v2 = acc[f][r] * a2v;
#pragma unroll
            for (int m = 1; m < 16; m <<= 1) {
                v1 += __shfl_xor(v1, m, 16);
                v2 += __shfl_xor(v2, m, 16);
            }
            if ((lane & 15) == 0) {
                atomicAdd(&sv[m0 + f * 16 + rb + r], v1);
                atomicAdd(&tv[m0 + f * 16 + rb + r], v2);
            }
        }
    }

    // ---- epilogue: transposed bf16 write via LDS ----
#pragma unroll
    for (int f = 0; f < 4; ++f)
#pragma unroll
        for (int r = 0; r < 4; ++r)
            Tr[w][lane & 15][f * 16 + rb + r] = f2bf(acc[f][r]);
    __syncthreads();
    const int c = lane >> 2, rowb = (lane & 3) * 16;
    const ushort* src = &Tr[w][c][rowb];
    const short8 v0 = *(const short8*)src;
    const short8 v1 = *(const short8*)(src + 8);
    ushort* dst = hTh + ((size_t)(m0 >> 11) * FOUT + n0 + w * 16 + c) * NN + (m0 & 2047) + rowb;
    *(short8*)dst = v0;
    *(short8*)(dst + 8) = v1;
}

// ---------------------------------------------------------------------------
// K2: fused masked softmax + P@H (MFMA) + elu.
// Block = 32 i-rows, one b (b = blockIdx&7 -> XCD L2 affinity for hT[b]).
// grid 512, 512 thr / 8 waves -> 2 blocks/CU. Per 64-j tile:
//   issue next adj + next H (direct global->VGPR frag loads, L2),
//   compute w = adj ? exp(lrelu(s_i+t_j)) : 0 -> bf16 -> P LDS (dbuf),
//   ONE barrier, ds_read P frags (b128, conflict-free), 8 MFMAs (setprio).
// den sums the rounded weights (softmax sums to exactly 1).
// ---------------------------------------------------------------------------
__global__ __launch_bounds__(512, 4) void gat_fused(const int* __restrict__ adj,
                                                    const ushort* __restrict__ hTh,
                                                    const float* __restrict__ sv,
                                                    const float* __restrict__ tv,
                                                    float* __restrict__ out) {
    __shared__ float t_l[NN];             // 8 KB
    __shared__ ushort Pf[2][2][2][512];   // 8 KB  [buf][ifrag][kstep][frag-lane*8]
    __shared__ float den_sl[32][17];      // 2.2 KB
    __shared__ float den_l[32];

    const int t = threadIdx.x, lane = t & 63, w = t >> 6;
    const int b = blockIdx.x & 7, i0 = (blockIdx.x >> 3) * 32;

    // stage t vector
    *(float4*)&t_l[t * 4] = *(const float4*)&tv[b * NN + t * 4];

    // P-writer mapping: q = [f:1][ks:1][l:6][half:1]
    const int pf_ = t >> 8, pks = (t >> 7) & 1, pl = (t >> 1) & 63, ph = t & 1;
    const int prow = (pf_ << 4) | (pl & 15);
    const int pj = (pks << 5) | ((pl >> 4) << 3) | (ph << 2);
    const int slot = ph | ((pl >> 4) << 1) | (pks << 3);
    const float s_i = sv[b * NN + i0 + prow];
    const int* adjp = adj + ((size_t)b * NN + i0 + prow) * NN + pj;
    ushort* pdst0 = &Pf[0][pf_][pks][pl * 8 + ph * 4];
    ushort* pdst1 = &Pf[1][pf_][pks][pl * 8 + ph * 4];

    // H direct-reg frag addresses (wave w owns cfrags 2w, 2w+1)
    const ushort* hb = hTh + (size_t)b * FOUT * NN;
    const ushort* h00 = hb + (size_t)(2 * w * 16 + (lane & 15)) * NN + (lane >> 4) * 8;
    const ushort* h10 = hb + (size_t)((2 * w + 1) * 16 + (lane & 15)) * NN + (lane >> 4) * 8;

    f32x4 acc[2][2];
#pragma unroll
    for (int f = 0; f < 2; ++f)
#pragma unroll
        for (int cf = 0; cf < 2; ++cf) acc[f][cf] = (f32x4){0.f, 0.f, 0.f, 0.f};
    float den_part = 0.f;

    // prologue: tile-0 adj + H
    int4 ajv = *(const int4*)adjp;
    short8 X00 = *(const short8*)h00, X01 = *(const short8*)(h00 + 32);
    short8 X10 = *(const short8*)h10, X11 = *(const short8*)(h10 + 32);
    short8 Y00, Y01, Y10, Y11;

    __syncthreads();   // t_l ready

    auto phase = [&](int jt, int rbuf, ushort* pdst,
                     short8& c00, short8& c01, short8& c10, short8& c11,
                     short8& n00, short8& n01, short8& n10, short8& n11) {
        const int j0 = jt * 64;
        const int jn = min(j0 + 64, NN - 64);   // clamped prefetch (dummy on last)
        // issue next-tile loads early (latency hides under exp + MFMA)
        const int4 ajn = *(const int4*)(adjp + jn);
        n00 = *(const short8*)(h00 + jn);
        n01 = *(const short8*)(h00 + jn + 32);
        n10 = *(const short8*)(h10 + jn);
        n11 = *(const short8*)(h10 + jn + 32);
        // weights for current tile
        const float4 tq = *(const float4*)&t_l[j0 + pj];
        const float tvv[4] = {tq.x, tq.y, tq.z, tq.w};
        const int avs[4] = {ajv.x, ajv.y, ajv.z, ajv.w};
        short4v pv;
#pragma unroll
        for (int e = 0; e < 4; ++e) {
            float v = s_i + tvv[e];
            v = v > 0.f ? v : LRALPHA * v;
            const float wv = avs[e] > 0 ? __expf(v) : 0.f;
            const ushort hbv = f2bf(wv);
            den_part += bf2f(hbv);
            pv[e] = (short)hbv;
        }
        *(short4v*)pdst = pv;
        ajv = ajn;
        __syncthreads();   // P(t) staged; WAR vs t-2 reads safe (barrier t-1 passed)
        // MFMA: read A frags (conflict-free b128), H already in regs
        const short8 a00 = *(const short8*)&Pf[rbuf][0][0][lane * 8];
        const short8 a01 = *(const short8*)&Pf[rbuf][0][1][lane * 8];
        const short8 a10 = *(const short8*)&Pf[rbuf][1][0][lane * 8];
        const short8 a11 = *(const short8*)&Pf[rbuf][1][1][lane * 8];
        __builtin_amdgcn_s_setprio(1);
        acc[0][0] = MFMA16(a00, c00, acc[0][0]);
        acc[0][0] = MFMA16(a01, c01, acc[0][0]);
        acc[0][1] = MFMA16(a00, c10, acc[0][1]);
        acc[0][1] = MFMA16(a01, c11, acc[0][1]);
        acc[1][0] = MFMA16(a10, c00, acc[1][0]);
        acc[1][0] = MFMA16(a11, c01, acc[1][0]);
        acc[1][1] = MFMA16(a10, c10, acc[1][1]);
        acc[1][1] = MFMA16(a11, c11, acc[1][1]);
        __builtin_amdgcn_s_setprio(0);
    };

    for (int tt = 0; tt < NN / 64; tt += 2) {
        phase(tt, 0, pdst0, X00, X01, X10, X11, Y00, Y01, Y10, Y11);
        phase(tt + 1, 1, pdst1, Y00, Y01, Y10, Y11, X00, X01, X10, X11);
    }

    // ---- denominator reduction ----
    den_sl[prow][slot] = den_part;
    __syncthreads();
    if (t < 32) {
        float s = 0.f;
#pragma unroll
        for (int k = 0; k < 16; ++k) s += den_sl[t][k];
        den_l[t] = s;
    }
    __syncthreads();

    // ---- epilogue: normalize + elu + store ----
    const int rb = (lane >> 4) * 4;
#pragma unroll
    for (int f = 0; f < 2; ++f) {
#pragma unroll
        for (int r = 0; r < 4; ++r) {
            const int row = f * 16 + rb + r;
            const float inv = 1.0f / den_l[row];
#pragma unroll
            for (int cf = 0; cf < 2; ++cf) {
                float v = acc[f][cf][r] * inv;
                v = v > 0.f ? v : expm1f(v);
                out[((size_t)b * NN + i0 + row) * FOUT + w * 32 + cf * 16 + (lane & 15)] = v;
            }
        }
    }
}

// ---------------------------------------------------------------------------
extern "C" void kernel_launch(void* const* d_in, const int* in_sizes, int n_in,
                              void* d_out, int out_size, void* d_ws, size_t ws_size,
                              hipStream_t stream) {
    const float* x   = (const float*)d_in[0];
    const int*   adj = (const int*)d_in[1];
    const float* W   = (const float*)d_in[2];
    const float* a   = (const float*)d_in[3];
    float* out = (float*)d_out;

    // ws: hTh 8MB | sv 64KB | tv 64KB | WTh 0.5MB | WTl 0.5MB
    ushort* hTh = (ushort*)d_ws;
    float*  sv  = (float*)(hTh + (size_t)Bb * FOUT * NN);
    float*  tv  = sv + Bb * NN;
    ushort* WTh = (ushort*)(tv + Bb * NN);
    ushort* WTl = WTh + (size_t)FIN * FOUT;

    hipMemsetAsync(sv, 0, 2 * (size_t)Bb * NN * sizeof(float), stream);
    prep_w<<<256, 256, 0, stream>>>(W, WTh, WTl);
    gemm_h<<<512, 512, 0, stream>>>(x, WTh, WTl, a, hTh, sv, tv);
    gat_fused<<<512, 512, 0, stream>>>(adj, hTh, sv, tv, out);
}